// Round 11
// baseline (272.744 us; speedup 1.0000x reference)
//
#include <hip/hip_runtime.h>
#include <stdint.h>

typedef unsigned long long u64;

#define A_TOTAL 43008
#define NB 16
#define NM 128
#define NBLK 84                   // x-blocks per batch; each owns 512 anchors
#define UPB 2                     // 256-anchor units per block
#define WPB 4                     // waves per block; grid = 1344 blocks
#define NBLOCKS (NBLK * NB)       // 1344 <= co-residency capacity 2048
#define POISON32 0xAAAAAAAAu      // harness ws poison pattern (u32)

// Bias for colfinal atomicMax: keys < 2^62, so OR 0xC000... is monotone, and
// the 0xAA ws-poison (0xAAAA... < 0xC000...) loses to every real key.
#define CBIAS 0xC000000000000000ull
#define CMASK 0x3FFFFFFFFFFFFFFFull

// Bit-exact fp32 division via Markstein sequence (R8-proven: absmax 0.0).
__device__ __forceinline__ float exact_div(float x, float y) {
    float r;
    asm("v_rcp_f32 %0, %1" : "=v"(r) : "v"(y));
    float e  = __builtin_fmaf(-y, r, 1.0f);
    r        = __builtin_fmaf(e, r, r);
    e        = __builtin_fmaf(-y, r, 1.0f);
    r        = __builtin_fmaf(e, r, r);
    float q  = x * r;
    float rs = __builtin_fmaf(-y, q, x);
    return __builtin_fmaf(rs, r, q);
}

// u64 cross-lane DPP max-merge helper (pairs stay inside aligned 8-lane octets).
__device__ __forceinline__ u64 dpp_u64(u64 v, const int ctrl) {
    int lo = (int)(unsigned)v, hi = (int)(unsigned)(v >> 32);
    int plo, phi;
    switch (ctrl) {
        case 0xB1:   // quad_perm [1,0,3,2] : xor 1
            plo = __builtin_amdgcn_update_dpp(lo, lo, 0xB1, 0xF, 0xF, false);
            phi = __builtin_amdgcn_update_dpp(hi, hi, 0xB1, 0xF, 0xF, false);
            break;
        case 0x4E:   // quad_perm [2,3,0,1] : xor 2
            plo = __builtin_amdgcn_update_dpp(lo, lo, 0x4E, 0xF, 0xF, false);
            phi = __builtin_amdgcn_update_dpp(hi, hi, 0x4E, 0xF, 0xF, false);
            break;
        default:     // 0x141 row_half_mirror : p -> 7-p within octet
            plo = __builtin_amdgcn_update_dpp(lo, lo, 0x141, 0xF, 0xF, false);
            phi = __builtin_amdgcn_update_dpp(hi, hi, 0x141, 0xF, 0xF, false);
            break;
    }
    return ((u64)(unsigned)phi << 32) | (unsigned)plo;
}

// ---------------------------------------------------------------------------
// Single persistent kernel: IoU pass (R10-proven math) -> device-wide wait on
// a done-counter -> inline epilogue. Row bests never leave registers.
// Grid 1344 blocks of 4 waves, all co-resident (cap 2048 via launch_bounds).
// ---------------------------------------------------------------------------
__global__ __launch_bounds__(256, 8) void all_kernel(
    const float4* __restrict__ anchors, const float* __restrict__ bb,
    const float4* __restrict__ bboxes, const int* __restrict__ labels,
    u64* __restrict__ colfinal,        // [NB][NM] biased atomicMax (no init)
    unsigned* __restrict__ done,       // starts at POISON32
    float* __restrict__ out_scores, float4* __restrict__ out_matched) {
#pragma clang fp contract(off)
    const int b = blockIdx.y, tid = threadIdx.x;
    const int lane = tid & 63, wv = tid >> 6;

    __shared__ float s_col[WPB][8][65];   // chunk transpose (2-way = free)
    __shared__ u64   s_ck[WPB][NM];       // per-wave col keys (both units)
    __shared__ float s_area[NM];          // box areas, once per block
    __shared__ float4 sbox[NM];           // phase 2
    __shared__ float  s_cm[NM];
    __shared__ int    s_lab[NM];
    __shared__ int    ovr[2 * 256];       // override window, block's 512 anchors

    if (tid < NM) {
        float4 v = bboxes[b * NM + tid];
        s_area[tid] = (v.z - v.x) * (v.w - v.y);
    }
    __syncthreads();

    const float* box = bb + (size_t)b * NM * 4;       // uniform -> s_load
    const int bi = lane >> 3, part = lane & 7;
    const int rbase = part * 8;

    float row_v[UPB]; int row_m[UPB];                 // row bests stay in regs

#pragma unroll
    for (int u = 0; u < UPB; ++u) {
        const int abase = (blockIdx.x * UPB + u) * 256 + wv * 64;

        float4 an = anchors[abase + lane];
        float hw = an.z * 0.5f, hh = an.w * 0.5f;
        float ax1 = an.x - hw, ay1 = an.y - hh;
        float ax2 = an.x + hw, ay2 = an.y + hh;
        float areaA = (ax2 - ax1) * (ay2 - ay1);

        float best_v = -1.0f; int best_m = 0;

        for (int c = 0; c < 16; ++c) {
#pragma unroll
            for (int i = 0; i < 8; ++i) {
                const int m = c * 8 + i;               // wave-uniform
                const float bx1 = box[4 * m + 0], by1 = box[4 * m + 1];
                const float bx2 = box[4 * m + 2], by2 = box[4 * m + 3];
                const float areaB = s_area[m];         // uniform ds broadcast

                float ltx = fmaxf(ax1, bx1), lty = fmaxf(ay1, by1);
                float rbx = fminf(ax2, bx2), rby = fminf(ay2, by2);
                float wx = fmaxf(rbx - ltx, 0.0f), wy = fmaxf(rby - lty, 0.0f);
                float inter = wx * wy;
                float iou = exact_div(inter, (areaA + areaB) - inter);

                if (iou > best_v) { best_v = iou; best_m = m; }  // first m tie
                s_col[wv][i][lane] = iou;
            }
            // col chunk reduce: 8 lanes (parts) per box, 8 serial entries each
            float v = -1.0f; int tb = 0;
#pragma unroll
            for (int t = 0; t < 8; ++t) {             // ascending anchor
                float o = s_col[wv][bi][rbase + t];
                if (o > v) { v = o; tb = t; }         // strict > : smallest t
            }
            unsigned aidx = (unsigned)((blockIdx.x * UPB + u) * 256 + wv * 64 +
                                       rbase + tb);
            u64 key = ((u64)__float_as_uint(v) << 32) | (u64)(unsigned)(~aidx);
            { u64 o = dpp_u64(key, 0xB1);  if (o > key) key = o; }
            { u64 o = dpp_u64(key, 0x4E);  if (o > key) key = o; }
            { u64 o = dpp_u64(key, 0x141); if (o > key) key = o; }
            if (part == 0) {
                if (u == 0) s_ck[wv][c * 8 + bi] = key;
                else {
                    u64 old = s_ck[wv][c * 8 + bi];
                    s_ck[wv][c * 8 + bi] = (key > old) ? key : old;
                }
            }
        }
        row_v[u] = best_v; row_m[u] = best_m;
    }

    __syncthreads();
    if (tid < NM) {
        u64 k = s_ck[0][tid];
        for (int w = 1; w < WPB; ++w) if (s_ck[w][tid] > k) k = s_ck[w][tid];
        atomicMax(&colfinal[b * NM + tid], CBIAS | k);
    }
    __threadfence();                    // release this block's col atomics
    __syncthreads();

    // ---- device-wide completion wait (all blocks co-resident by design) ----
    if (tid == 0) {
        atomicAdd(done, 1u);
        unsigned v;
        do {
            __builtin_amdgcn_s_sleep(2);
            v = __hip_atomic_load(done, __ATOMIC_ACQUIRE,
                                  __HIP_MEMORY_SCOPE_AGENT);
        } while ((unsigned)(v - POISON32) < (unsigned)NBLOCKS);
    }
    __syncthreads();

    // ---- phase 2: override window + score + matched gather ----
    const int blockbase = blockIdx.x * (UPB * 256);
    ovr[tid] = -1; ovr[tid + 256] = -1;

    int my_ca = -1;
    if (tid < NM) {
        u64 k = __hip_atomic_load(&colfinal[b * NM + tid], __ATOMIC_RELAXED,
                                  __HIP_MEMORY_SCOPE_AGENT) & CMASK;
        s_cm[tid] = __uint_as_float((unsigned)(k >> 32));
        my_ca = ~((int)(unsigned)(k & 0xFFFFFFFFull));   // recover anchor idx
        sbox[tid]  = bboxes[b * NM + tid];
        s_lab[tid] = labels[b * NM + tid];
    }
    __syncthreads();
    if (tid < NM && my_ca >= blockbase && my_ca < blockbase + UPB * 256)
        atomicMax(&ovr[my_ca - blockbase], tid);         // later j wins == max j
    __syncthreads();

#pragma unroll
    for (int u = 0; u < UPB; ++u) {
        const int a = blockbase + u * 256 + wv * 64 + lane;
        float best = row_v[u];
        int   bidx = row_m[u];

        int o = ovr[a - blockbase];
        if (o >= 0) { bidx = o; best = s_cm[o]; }

        float denom = fmaxf(s_cm[bidx], 0.3f);        // IOU_THR
        float val   = (best < 0.15f) ? 0.0f : best;   // IOU_THR * 0.5
        float score = val / denom;
        if (s_lab[bidx] <= 0) score = 0.0f;

        out_scores[(size_t)b * A_TOTAL + a]  = score;
        out_matched[(size_t)b * A_TOTAL + a] = sbox[bidx];
    }
}

extern "C" void kernel_launch(void* const* d_in, const int* in_sizes, int n_in,
                              void* d_out, int out_size, void* d_ws, size_t ws_size,
                              hipStream_t stream) {
    const int*    labels  = (const int*)d_in[0];     // [NB, NM] int32
    const float4* bboxes  = (const float4*)d_in[1];  // [NB, NM, 4] xyxy
    const float4* anchors = (const float4*)d_in[2];  // [A_TOTAL, 4] cxcywh

    float*  out_scores  = (float*)d_out;             // scores [NB,A]
    float4* out_matched = (float4*)((float*)d_out + (size_t)NB * A_TOTAL);

    char* ws = (char*)d_ws;
    u64*      colfinal = (u64*)ws;                   ws += (size_t)NB * NM * 8;
    unsigned* done     = (unsigned*)ws;              // starts at POISON32

    dim3 g(NBLK, NB);
    all_kernel<<<g, 256, 0, stream>>>(anchors, (const float*)bboxes, bboxes,
                                      labels, colfinal, done,
                                      out_scores, out_matched);
}

// Round 12
// 132.724 us; speedup vs baseline: 2.0550x; 2.0550x over previous
//
#include <hip/hip_runtime.h>
#include <stdint.h>

typedef unsigned long long u64;

#define A_TOTAL 43008
#define NB 16
#define NM 128
#define SPLIT 168                 // blocks per batch; 4 waves; 64 anchors/lane-wave
#define WPB 4
#define CPB 8                     // chunks per box-loop: 8 chunks x 16 boxes

// Bit-exact fp32 division via Markstein sequence (R8-proven: absmax 0.0).
__device__ __forceinline__ float exact_div(float x, float y) {
    float r;
    asm("v_rcp_f32 %0, %1" : "=v"(r) : "v"(y));
    float e  = __builtin_fmaf(-y, r, 1.0f);
    r        = __builtin_fmaf(e, r, r);
    e        = __builtin_fmaf(-y, r, 1.0f);
    r        = __builtin_fmaf(e, r, r);
    float q  = x * r;
    float rs = __builtin_fmaf(-y, q, x);
    return __builtin_fmaf(rs, r, q);
}

// u64 cross-lane DPP max-merge helper (pairs stay inside aligned quads).
__device__ __forceinline__ u64 dpp_u64(u64 v, const int ctrl) {
    int lo = (int)(unsigned)v, hi = (int)(unsigned)(v >> 32);
    int plo, phi;
    if (ctrl == 0xB1) {          // quad_perm [1,0,3,2] : xor 1
        plo = __builtin_amdgcn_update_dpp(lo, lo, 0xB1, 0xF, 0xF, false);
        phi = __builtin_amdgcn_update_dpp(hi, hi, 0xB1, 0xF, 0xF, false);
    } else {                     // quad_perm [2,3,0,1] : xor 2
        plo = __builtin_amdgcn_update_dpp(lo, lo, 0x4E, 0xF, 0xF, false);
        phi = __builtin_amdgcn_update_dpp(hi, hi, 0x4E, 0xF, 0xF, false);
    }
    return ((u64)(unsigned)phi << 32) | (unsigned)plo;
}

// Tiny prep: bbox areas [NB*NM] + zero-init colfinal [NB*NM]. 8 blocks x 256.
__global__ __launch_bounds__(256) void prep_kernel(
    const float4* __restrict__ bboxes, float* __restrict__ areaBp,
    u64* __restrict__ colfinal) {
#pragma clang fp contract(off)
    const int i = blockIdx.x * 256 + threadIdx.x;    // 0..2047
    float4 v = bboxes[i];
    areaBp[i] = (v.z - v.x) * (v.w - v.y);
    colfinal[i] = 0ull;
}

// ---------------------------------------------------------------------------
// Fused IoU pass (R8 structure, 2 boxes/iter): lane = anchor, loop = box-pair.
// 64 iterations of (2i, 2i+1) keep ascending-m order for jnp argmax ties.
// Row (per-anchor): private update, 2-box pre-merge (strict > picks m1).
// Box coords/areas: wave-uniform s_loads. Col (per-box): f32 LDS transpose
// per 16-box chunk (writes 2-way = free), 4 lanes/box x 16 serial entries
// (ascending anchor -> strict '>' = smallest anchor), pack (iou<<32)|(~a),
// 2 quad-DPP u64 merges, per-wave stage, block-merge, device atomicMax.
// ---------------------------------------------------------------------------
__global__ __launch_bounds__(256) void fused_kernel(
    const float4* __restrict__ anchors, const float* __restrict__ bb,
    const float* __restrict__ areaBp,
    u64* __restrict__ rowkey,        // [NB][A_TOTAL] (iou_bits<<32)|m
    u64* __restrict__ colfinal) {    // [NB][NM] atomicMax table
#pragma clang fp contract(off)
    const int b = blockIdx.y, tid = threadIdx.x;
    const int lane = tid & 63, wv = tid >> 6;
    const int abase = blockIdx.x * 256 + wv * 64;

    __shared__ float s_col[WPB][16][65];  // 16-box chunk transpose
    __shared__ u64   s_ck[WPB][NM];       // per-wave col keys

    // this lane's anchor, converted once (amortized over 64 pair-iters)
    float4 an = anchors[abase + lane];
    float hw = an.z * 0.5f, hh = an.w * 0.5f;
    float ax1 = an.x - hw, ay1 = an.y - hh;
    float ax2 = an.x + hw, ay2 = an.y + hh;
    float areaA = (ax2 - ax1) * (ay2 - ay1);

    const float* box  = bb + (size_t)b * NM * 4;      // uniform -> s_load
    const float* area = areaBp + (size_t)b * NM;

    float best_v = -1.0f; int best_m = 0;             // private row state
    const int bi = lane >> 2, part = lane & 3;        // col reduce: 4 lanes/box
    const int rbase = part * 16;

    for (int c = 0; c < CPB; ++c) {
#pragma unroll
        for (int i = 0; i < 8; ++i) {
            const int m0 = c * 16 + 2 * i;             // wave-uniform
            const int m1 = m0 + 1;
            const float b0x1 = box[4 * m0 + 0], b0y1 = box[4 * m0 + 1];
            const float b0x2 = box[4 * m0 + 2], b0y2 = box[4 * m0 + 3];
            const float b1x1 = box[4 * m1 + 0], b1y1 = box[4 * m1 + 1];
            const float b1x2 = box[4 * m1 + 2], b1y2 = box[4 * m1 + 3];
            const float areaB0 = area[m0], areaB1 = area[m1];

            float ltx0 = fmaxf(ax1, b0x1), lty0 = fmaxf(ay1, b0y1);
            float rbx0 = fminf(ax2, b0x2), rby0 = fminf(ay2, b0y2);
            float wx0 = fmaxf(rbx0 - ltx0, 0.0f), wy0 = fmaxf(rby0 - lty0, 0.0f);
            float in0 = wx0 * wy0;
            float iou0 = exact_div(in0, (areaA + areaB0) - in0);

            float ltx1 = fmaxf(ax1, b1x1), lty1 = fmaxf(ay1, b1y1);
            float rbx1 = fminf(ax2, b1x2), rby1 = fminf(ay2, b1y2);
            float wx1 = fmaxf(rbx1 - ltx1, 0.0f), wy1 = fmaxf(rby1 - lty1, 0.0f);
            float in1 = wx1 * wy1;
            float iou1 = exact_div(in1, (areaA + areaB1) - in1);

            // row: in-pair winner (strict > picks m1 -> first-m on tie),
            // then running best (strict > -> first-m across iters)
            float pv = fmaxf(iou0, iou1);
            int   pm = (iou1 > iou0) ? m1 : m0;
            if (pv > best_v) { best_v = pv; best_m = pm; }

            s_col[wv][2 * i + 0][lane] = iou0;
            s_col[wv][2 * i + 1][lane] = iou1;
        }
        // col chunk reduce: 4 lanes (parts) per box, 16 serial entries each
        float v = -1.0f; int tb = 0;
#pragma unroll
        for (int t = 0; t < 16; ++t) {                // ascending anchor
            float o = s_col[wv][bi][rbase + t];
            if (o > v) { v = o; tb = t; }             // strict > : smallest t
        }
        unsigned aidx = (unsigned)(abase + rbase + tb);
        u64 key = ((u64)__float_as_uint(v) << 32) | (u64)(unsigned)(~aidx);
        { u64 o = dpp_u64(key, 0xB1); if (o > key) key = o; }   // xor 1
        { u64 o = dpp_u64(key, 0x4E); if (o > key) key = o; }   // xor 2
        if (part == 0) s_ck[wv][c * 16 + bi] = key;
    }

    rowkey[(size_t)b * A_TOTAL + abase + lane] =
        ((u64)__float_as_uint(best_v) << 32) | (u64)(unsigned)best_m;

    __syncthreads();
    if (tid < NM) {
        u64 k = s_ck[0][tid];
        for (int w = 1; w < WPB; ++w) if (s_ck[w][tid] > k) k = s_ck[w][tid];
        atomicMax(&colfinal[b * NM + tid], k);
    }
}

// Streaming epilogue (R5-proven): per-block override window + score + gather.
__global__ __launch_bounds__(256) void epilogue_kernel(
    const float4* __restrict__ bboxes, const int* __restrict__ labels,
    const u64* __restrict__ colfinal, const u64* __restrict__ rowkey,
    float* __restrict__ out_scores, float4* __restrict__ out_matched) {
#pragma clang fp contract(off)
    const int b = blockIdx.y, tid = threadIdx.x;
    const int a0 = blockIdx.x * 256, a = a0 + tid;   // A_TOTAL == 168*256

    __shared__ float4 sbox[NM];
    __shared__ float  s_cm[NM];
    __shared__ int    s_lab[NM];
    __shared__ int    ovr[256];
    ovr[tid] = -1;

    int my_ca = -1;
    if (tid < NM) {
        u64 k = colfinal[b * NM + tid];
        s_cm[tid] = __uint_as_float((unsigned)(k >> 32));
        my_ca = ~((int)(unsigned)(k & 0xFFFFFFFFull));   // recover anchor idx
        sbox[tid]  = bboxes[b * NM + tid];
        s_lab[tid] = labels[b * NM + tid];
    }
    __syncthreads();
    if (tid < NM && my_ca >= a0 && my_ca < a0 + 256)
        atomicMax(&ovr[my_ca - a0], tid);                // later j wins == max j
    __syncthreads();

    u64 rk = rowkey[(size_t)b * A_TOTAL + a];
    float best = __uint_as_float((unsigned)(rk >> 32));
    int   bi   = (int)(rk & 0xFFFFFFFFull);

    int o = ovr[tid];
    if (o >= 0) { bi = o; best = s_cm[o]; }

    float denom = fmaxf(s_cm[bi], 0.3f);        // IOU_THR
    float val   = (best < 0.15f) ? 0.0f : best; // IOU_THR * 0.5
    float score = val / denom;
    if (s_lab[bi] <= 0) score = 0.0f;

    out_scores[(size_t)b * A_TOTAL + a]  = score;
    out_matched[(size_t)b * A_TOTAL + a] = sbox[bi];
}

extern "C" void kernel_launch(void* const* d_in, const int* in_sizes, int n_in,
                              void* d_out, int out_size, void* d_ws, size_t ws_size,
                              hipStream_t stream) {
    const int*    labels  = (const int*)d_in[0];     // [NB, NM] int32
    const float4* bboxes  = (const float4*)d_in[1];  // [NB, NM, 4] xyxy
    const float4* anchors = (const float4*)d_in[2];  // [A_TOTAL, 4] cxcywh

    float* out = (float*)d_out;                      // scores [NB,A], matched [NB,A,4]

    char* ws = (char*)d_ws;
    u64*   rowkey   = (u64*)ws;                      ws += (size_t)NB * A_TOTAL * 8;
    u64*   colfinal = (u64*)ws;                      ws += (size_t)NB * NM * 8;
    float* areaBp   = (float*)ws;

    prep_kernel<<<(NB * NM) / 256, 256, 0, stream>>>(bboxes, areaBp, colfinal);

    dim3 g(SPLIT, NB);
    fused_kernel<<<g, 256, 0, stream>>>(anchors, (const float*)bboxes, areaBp,
                                        rowkey, colfinal);
    epilogue_kernel<<<g, 256, 0, stream>>>(
        bboxes, labels, colfinal, rowkey,
        out, (float4*)(out + (size_t)NB * A_TOTAL));
}